// Round 13
// baseline (439.466 us; speedup 1.0000x reference)
//
#include <hip/hip_runtime.h>
#include <math.h>

#define NB   256
#define ND   63
#define NN   3969        // 63*63

__device__ __forceinline__ float gelu_f(float v){
    return 0.5f * v * (1.0f + erff(v * 0.70710678118654752440f));
}

#define FMA4(A, W, S) { (A).x=fmaf((W).x,(S),(A).x); (A).y=fmaf((W).y,(S),(A).y); \
                        (A).z=fmaf((W).z,(S),(A).z); (A).w=fmaf((W).w,(S),(A).w); }

union F4 { float4 v; float a[4]; };
union W16 { float4 v[4]; float a[16]; };

// ---- fused ct1..ct3 per sample. Raw weights transposed in-block; c1/c2 in
// ---- LDS; c3 (17x17x32 channel-last) to global. --------------------------
__global__ __launch_bounds__(512) void k_ct123(const float* __restrict__ kA,
                                               const float* __restrict__ cw1,
                                               const float* __restrict__ cw2,
                                               const float* __restrict__ cw3,
                                               const float* __restrict__ b1,
                                               const float* __restrict__ b2,
                                               const float* __restrict__ b3,
                                               float* __restrict__ c3out,
                                               float* __restrict__ acc){
    __shared__ __align__(16) float wbuf[9216];   // [tap][ci][co32]
    __shared__ float w1s[288];                   // [tap][co32]
    __shared__ float c1s[25*33];                 // [px][ci] stride 33
    __shared__ float c2s[81*33];
    __shared__ float b1s[32], b2s[32], b3s[32];
    const int b = blockIdx.x, tid = threadIdx.x;
    if (b == 0 && tid == 0) acc[0] = 0.f;
    for (int j = tid; j < 9216; j += 512){
        int tap = j >> 10, ci = (j >> 5) & 31, co = j & 31;
        wbuf[j] = cw2[(ci*32 + co)*9 + tap];
    }
    if (tid < 288) w1s[(tid % 9)*32 + tid/9] = cw1[tid];
    if (tid < 32){ b1s[tid]=b1[tid]; b2s[tid]=b2[tid]; b3s[tid]=b3[tid]; }
    __syncthreads();
    // ---- ct1: 3x3 -> 5x5, 1->32. 200 units ----
    if (tid < 200){
        int px = tid >> 3, q = tid & 7;
        int oy = px / 5, ox = px % 5;
        F4 a4; a4.v = ((const float4*)b1s)[q];
        int nky, kyA[2], iyA[2];
        if (oy & 1){ nky=2; kyA[0]=0; iyA[0]=(oy+1)/2; kyA[1]=2; iyA[1]=(oy-1)/2; }
        else       { nky=1; kyA[0]=1; iyA[0]=oy/2; kyA[1]=1; iyA[1]=0; }
        int nkx, kxA[2], ixA[2];
        if (ox & 1){ nkx=2; kxA[0]=0; ixA[0]=(ox+1)/2; kxA[1]=2; ixA[1]=(ox-1)/2; }
        else       { nkx=1; kxA[0]=1; ixA[0]=ox/2; kxA[1]=1; ixA[1]=0; }
        const float* ab = kA + b*9;
        for (int yi = 0; yi < nky; yi++)
        for (int xi = 0; xi < nkx; xi++){
            float v = ab[iyA[yi]*3 + ixA[xi]];
            float4 w = *(const float4*)(w1s + (kyA[yi]*3 + kxA[xi])*32 + 4*q);
            FMA4(a4.v, w, v);
        }
        float* op = c1s + px*33 + 4*q;
        op[0]=gelu_f(a4.a[0]); op[1]=gelu_f(a4.a[1]);
        op[2]=gelu_f(a4.a[2]); op[3]=gelu_f(a4.a[3]);
    }
    __syncthreads();
    // ---- ct2: 5->9 ----
    for (int u = tid; u < 648; u += 512){
        int px = u >> 3, q = u & 7;
        int oy = px / 9, ox = px % 9;
        F4 a4; a4.v = ((const float4*)b2s)[q];
        int nky, kyA[2], iyA[2];
        if (oy & 1){ nky=2; kyA[0]=0; iyA[0]=(oy+1)/2; kyA[1]=2; iyA[1]=(oy-1)/2; }
        else       { nky=1; kyA[0]=1; iyA[0]=oy/2; kyA[1]=1; iyA[1]=0; }
        int nkx, kxA[2], ixA[2];
        if (ox & 1){ nkx=2; kxA[0]=0; ixA[0]=(ox+1)/2; kxA[1]=2; ixA[1]=(ox-1)/2; }
        else       { nkx=1; kxA[0]=1; ixA[0]=ox/2; kxA[1]=1; ixA[1]=0; }
        for (int yi = 0; yi < nky; yi++)
        for (int xi = 0; xi < nkx; xi++){
            const float* ip = c1s + (iyA[yi]*5 + ixA[xi])*33;
            const float* wp = wbuf + (kyA[yi]*3 + kxA[xi])*1024 + 4*q;
            #pragma unroll 8
            for (int ci = 0; ci < 32; ci++){
                float v = ip[ci];
                float4 w = *(const float4*)(wp + ci*32);
                FMA4(a4.v, w, v);
            }
        }
        float* op = c2s + px*33 + 4*q;
        op[0]=gelu_f(a4.a[0]); op[1]=gelu_f(a4.a[1]);
        op[2]=gelu_f(a4.a[2]); op[3]=gelu_f(a4.a[3]);
    }
    __syncthreads();
    for (int j = tid; j < 9216; j += 512){
        int tap = j >> 10, ci = (j >> 5) & 31, co = j & 31;
        wbuf[j] = cw3[(ci*32 + co)*9 + tap];
    }
    __syncthreads();
    // ---- ct3: 9->17, channel-last to global ----
    float* ob = c3out + (size_t)b * (289*32);
    for (int u = tid; u < 2312; u += 512){
        int px = u >> 3, q = u & 7;
        int oy = px / 17, ox = px % 17;
        F4 a4; a4.v = ((const float4*)b3s)[q];
        int nky, kyA[2], iyA[2];
        if (oy & 1){ nky=2; kyA[0]=0; iyA[0]=(oy+1)/2; kyA[1]=2; iyA[1]=(oy-1)/2; }
        else       { nky=1; kyA[0]=1; iyA[0]=oy/2; kyA[1]=1; iyA[1]=0; }
        int nkx, kxA[2], ixA[2];
        if (ox & 1){ nkx=2; kxA[0]=0; ixA[0]=(ox+1)/2; kxA[1]=2; ixA[1]=(ox-1)/2; }
        else       { nkx=1; kxA[0]=1; ixA[0]=ox/2; kxA[1]=1; ixA[1]=0; }
        for (int yi = 0; yi < nky; yi++)
        for (int xi = 0; xi < nkx; xi++){
            const float* ip = c2s + (iyA[yi]*9 + ixA[xi])*33;
            const float* wp = wbuf + (kyA[yi]*3 + kxA[xi])*1024 + 4*q;
            #pragma unroll 8
            for (int ci = 0; ci < 32; ci++){
                float v = ip[ci];
                float4 w = *(const float4*)(wp + ci*32);
                FMA4(a4.v, w, v);
            }
        }
        float4 g;
        g.x=gelu_f(a4.a[0]); g.y=gelu_f(a4.a[1]);
        g.z=gelu_f(a4.a[2]); g.w=gelu_f(a4.a[3]);
        *(float4*)(ob + (size_t)px*32 + 4*q) = g;
    }
}

// ------------- ct4 32->32, 17->33, stride2 pad1 k3, gelu, channel-last.
// 2 blocks/sample (16 waves/CU), 8-px x 8-co register tiles (r11-proven).
// Weight transpose done in staging (raw cw4 -> [tap][ci][co32] in LDS).
__global__ __launch_bounds__(512) void k_ct4(const float* __restrict__ in,
                                             const float* __restrict__ cw4,
                                             const float* __restrict__ bias,
                                             float* __restrict__ out){
    constexpr int HIN = 17, HOUT = 33, HINP = 20;
    constexpr int OCT  = (HOUT + 7) / 8;        // 5
    constexpr int UPR  = OCT * 4;               // 20
    constexpr int NODD = (HOUT/2) * UPR;        // 320
    constexpr int TOT  = HOUT * UPR;            // 660
    constexpr int HT   = (TOT + 1) / 2;         // 330
    constexpr int INEL = 32*HIN*HINP;           // 10880
    __shared__ __align__(16) float lds[INEL + 9216 + 32];
    float* in_s   = lds;
    float* w_s    = lds + INEL;
    float* bias_s = lds + INEL + 9216;
    const int b = blockIdx.x >> 1, h = blockIdx.x & 1;
    const int tid = threadIdx.x;
    for (int j = tid; j < 9216; j += 512){
        int tap = j >> 10, ci = (j >> 5) & 31, co = j & 31;
        w_s[j] = cw4[(ci*32 + co)*9 + tap];
    }
    if (tid < 32) bias_s[tid] = bias[tid];
    { const float* gi = in + (size_t)b * (32*HIN*HIN);
      for (int i = tid; i < 32*HIN*HIN; i += 512){
        int ci = i & 31, px = i >> 5;
        int y = px / HIN, x = px % HIN;
        in_s[ci*(HIN*HINP) + y*HINP + x] = gi[i];
      } }
    __syncthreads();
    float* ob0 = out + (size_t)b*(HOUT*HOUT*32);
    const int u0 = h*HT, u1 = (u0 + HT < TOT) ? (u0 + HT) : TOT;
    for (int u = u0 + tid; u < u1; u += 512){
        int r, s;
        if (u < NODD){ r = 2*(u/UPR) + 1; s = u % UPR; }
        else { int v = u - NODD; r = 2*(v/UPR); s = v % UPR; }
        const int m = s >> 2, cog = s & 3;
        const int x4 = 4*m;
        F4 acc[8][2];
        { float4 b0 = ((const float4*)bias_s)[cog*2];
          float4 b1 = ((const float4*)bias_s)[cog*2+1];
          #pragma unroll
          for (int p = 0; p < 8; p++){ acc[p][0].v = b0; acc[p][1].v = b1; } }
        int nky, kyA[2], iyA[2];
        if (r & 1){ int rI = r >> 1; nky = 2; kyA[0]=0; iyA[0]=rI+1; kyA[1]=2; iyA[1]=rI; }
        else      { nky = 1; kyA[0]=1; iyA[0]= r >> 1; kyA[1]=1; iyA[1]=0; }
        for (int yi = 0; yi < nky; yi++){
            const float* ip = in_s + iyA[yi]*HINP + x4;
            const float* wp = w_s + kyA[yi]*3*1024 + cog*8;
            #pragma unroll 2
            for (int ci = 0; ci < 32; ci++){
                F4 iv0, iv1;
                iv0.v = *(const float4*)(ip);
                iv1.v = *(const float4*)(ip + 4);
                float4 w0a = *(const float4*)(wp);
                float4 w0b = *(const float4*)(wp + 4);
                float4 w1a = *(const float4*)(wp + 1024);
                float4 w1b = *(const float4*)(wp + 1028);
                float4 w2a = *(const float4*)(wp + 2048);
                float4 w2b = *(const float4*)(wp + 2052);
                #pragma unroll
                for (int p = 0; p < 4; p++){
                    float ev = iv0.a[p];
                    FMA4(acc[2*p][0].v, w1a, ev);
                    FMA4(acc[2*p][1].v, w1b, ev);
                    float o0 = (p < 3) ? iv0.a[p+1] : iv1.a[0];
                    FMA4(acc[2*p+1][0].v, w0a, o0);
                    FMA4(acc[2*p+1][1].v, w0b, o0);
                    FMA4(acc[2*p+1][0].v, w2a, ev);
                    FMA4(acc[2*p+1][1].v, w2b, ev);
                }
                ip += HIN*HINP;
                wp += 32;
            }
        }
        int lim = HOUT - 8*m; if (lim > 8) lim = 8;
        float* ob = ob0 + ((size_t)r*HOUT + 8*m)*32 + cog*8;
        for (int e = 0; e < lim; e++){
            float4 g0, g1;
            g0.x=gelu_f(acc[e][0].a[0]); g0.y=gelu_f(acc[e][0].a[1]);
            g0.z=gelu_f(acc[e][0].a[2]); g0.w=gelu_f(acc[e][0].a[3]);
            g1.x=gelu_f(acc[e][1].a[0]); g1.y=gelu_f(acc[e][1].a[1]);
            g1.z=gelu_f(acc[e][1].a[2]); g1.w=gelu_f(acc[e][1].a[3]);
            *(float4*)(ob + (size_t)e*32)     = g0;
            *(float4*)(ob + (size_t)e*32 + 4) = g1;
        }
    }
}

// ---------------- mega solver, 512 threads, Hermitian-halved DFT -------------
// Identical to r12's proven kernel (hyper MLP + ct5 + v-build + tables fused).
__global__ __launch_bounds__(512) void k_solve(const float* __restrict__ x0g,
                                               const float* __restrict__ f,
                                               const float* __restrict__ kAg,
                                               const float* __restrict__ w1a, const float* __restrict__ b1a,
                                               const float* __restrict__ w2a, const float* __restrict__ b2a,
                                               const float* __restrict__ w1b, const float* __restrict__ b1b,
                                               const float* __restrict__ w2b, const float* __restrict__ b2b,
                                               const float* __restrict__ cw5,
                                               const float* __restrict__ b5,
                                               const float* __restrict__ c4g,
                                               float* __restrict__ accg){
    __shared__ __align__(16) float xs[63*68 + 8];
    __shared__ __align__(16) float U[8576];
    __shared__ __align__(16) float Fs_r[4096];
    __shared__ __align__(16) float Fs_i[4096];
    __shared__ __align__(16) float vcs[4096];
    __shared__ float ws5b[576];
    __shared__ float w1s[148], w2s[148], dvs[64], ds_r[32], ds_i[32], red[8], hs[100];
    const int b = blockIdx.x, tid = threadIdx.x;
    float* rs = U;
    float* tc = U + 4288;
    float*  rP  = U;
    const float4* rP4 = (const float4*)U;
    float2* TtC = (float2*)(U + 4096);
    float2* MC2 = (float2*)U;
    float4* CC4 = (float4*)(U + 4096);
    float* c5s = U;
    const float4* F4r = (const float4*)Fs_r;
    const float4* F4i = (const float4*)Fs_i;
    const float4* vc4s = (const float4*)vcs;
    const float* fg = f + (size_t)b*NN;
    float ka[9];
    #pragma unroll
    for (int i = 0; i < 9; i++) ka[i] = kAg[b*9 + i];

    // ================= prologue =================
    for (int i = tid; i < 4096; i += 512){
        int r = i >> 6, c = i & 63;
        float vr = 0.f, vi = 0.f;
        if (r < 63 && c < 63){
            int m = (r * c) % 63;
            float ang = 6.283185307179586f * (float)m / 63.0f;
            vr = cosf(ang); vi = -sinf(ang);
        }
        Fs_r[i] = vr; Fs_i[i] = vi;
    }
    for (int i = tid; i < 576; i += 512){
        int ci = i / 18, co = (i / 9) & 1, tap = i % 9;
        ws5b[tap*64 + ci*2 + co] = cw5[i];
    }
    for (int i = tid; i < NN; i += 512) xs[(i/ND)*68 + (i%ND)] = x0g[(size_t)b*NN + i];
    if (tid < 100){
        float s = b1a[tid];
        #pragma unroll
        for (int i = 0; i < 9; i++) s = fmaf(ka[i], w1a[i*100 + tid], s);
        hs[tid] = gelu_f(s);
    }
    __syncthreads();
    if (tid < 147){
        float s = b2a[tid];
        for (int k = 0; k < 100; k++) s = fmaf(hs[k], w2a[k*147 + tid], s);
        w1s[tid] = s;
    }
    __syncthreads();
    if (tid < 100){
        float s = b1b[tid];
        #pragma unroll
        for (int i = 0; i < 9; i++) s = fmaf(ka[i], w1b[i*100 + tid], s);
        hs[tid] = gelu_f(s);
    }
    __syncthreads();
    if (tid < 147){
        float s = b2b[tid];
        for (int k = 0; k < 100; k++) s = fmaf(hs[k], w2b[k*147 + tid], s);
        w2s[tid] = s;
    }
    {
        const float* ib = c4g + (size_t)b * (1089*32);
        float bb0 = b5[0], bb1 = b5[1];
        for (int p = tid; p < NN; p += 512){
            int oy = p / ND, ox = p % ND;
            float a0 = bb0, a1 = bb1;
            int nky, kyA[2], iyA[2];
            if ((oy & 1) == 0){ nky=2; kyA[0]=0; iyA[0]=oy/2+1; kyA[1]=2; iyA[1]=oy/2; }
            else              { nky=1; kyA[0]=1; iyA[0]=(oy+1)/2; kyA[1]=1; iyA[1]=0; }
            int nkx, kxA[2], ixA[2];
            if ((ox & 1) == 0){ nkx=2; kxA[0]=0; ixA[0]=ox/2+1; kxA[1]=2; ixA[1]=ox/2; }
            else              { nkx=1; kxA[0]=1; ixA[0]=(ox+1)/2; kxA[1]=1; ixA[1]=0; }
            for (int yi = 0; yi < nky; yi++)
            for (int xi = 0; xi < nkx; xi++){
                const float* ip = ib + ((size_t)iyA[yi]*33 + ixA[xi])*32;
                const float* wp = ws5b + (kyA[yi]*3 + kxA[xi])*64;
                #pragma unroll
                for (int g = 0; g < 8; g++){
                    F4 iv; iv.v = *(const float4*)(ip + 4*g);
                    #pragma unroll
                    for (int q = 0; q < 4; q++){
                        int ci = 4*g + q;
                        a0 = fmaf(iv.a[q], wp[ci*2],   a0);
                        a1 = fmaf(iv.a[q], wp[ci*2+1], a1);
                    }
                }
            }
            c5s[p]      = a0;
            c5s[NN + p] = a1;
        }
    }
    __syncthreads();
    {
        const float sc = 1.0f / 3969.0f;
        float4* vout = (float4*)vcs;
        for (int i = tid; i < 1024; i += 512){
            int ky = i >> 5, ct2 = i & 31;
            float4 o;
            #pragma unroll
            for (int j = 0; j < 2; j++){
                int kx = 2*ct2 + j;
                float re = 0.f, im = 0.f;
                if (kx <= 31){ int o2 = 2*(ky*ND + kx); re = c5s[o2]*sc; im = c5s[o2+1]*sc; }
                else if (kx <= 62){
                    int sy = (ND - ky) % ND, sx = ND - kx;
                    int o2 = 2*(sy*ND + sx); re = c5s[o2]*sc; im = -c5s[o2+1]*sc;
                }
                if (j == 0){ o.x = re; o.y = im; } else { o.z = re; o.w = im; }
            }
            vout[i] = o;
        }
        if (tid < 32){
            float2 d = {0.f, 0.f};
            if (tid >= 1){
                int iA = (ND - tid) * ND, iB = tid * ND;
                d.x = (c5s[2*iA]     - c5s[2*iB])     * sc;
                d.y = (c5s[2*iA + 1] + c5s[2*iB + 1]) * sc;
            }
            ((float2*)dvs)[tid] = d;
        }
    }
    __syncthreads();

    const int kt = tid >> 4, cg = tid & 15;

    for (int it = 0; it < 5; it++){
        { float4 z = {0.f,0.f,0.f,0.f}; float4* U4 = (float4*)U;
          for (int i = tid; i < 2144; i += 512) U4[i] = z; }
        __syncthreads();
        for (int i = tid; i < NN; i += 512){
            int y = i / ND, xx = i % ND;
            float s = 0.f;
            #pragma unroll
            for (int dy = 0; dy < 3; dy++){
                int u = y + dy;
                #pragma unroll
                for (int dx = 0; dx < 3; dx++){
                    int v = xx + dx;
                    float p;
                    if (u == 64 || v == 64)    p = 1.0f;
                    else if (u == 0 || v == 0) p = 0.0f;
                    else                       p = xs[(u-1)*68 + (v-1)];
                    s = fmaf(p, ka[dy*3 + dx], s);
                }
            }
            rs[y*68 + 3 + xx] = fg[i] - s;
        }
        __syncthreads();
        const bool act = tid < 504;
        const int y0 = tid >> 3, x0c = 8*(tid & 7);
        float acc2[8] = {};
        for (int c = 0; c < 3; c++){
            if (act){
                float a1[8] = {};
                for (int dy = 0; dy < 7; dy++){
                    int ry = y0 + dy - 3;
                    if (ry < 0 || ry >= 63) continue;
                    W16 w16;
                    const float4* rp = (const float4*)(rs + ry*68 + x0c);
                    w16.v[0]=rp[0]; w16.v[1]=rp[1]; w16.v[2]=rp[2]; w16.v[3]=rp[3];
                    #pragma unroll
                    for (int dx = 0; dx < 7; dx++){
                        float wv = w1s[c*49 + dy*7 + dx];
                        #pragma unroll
                        for (int t = 0; t < 8; t++) a1[t] = fmaf(wv, w16.a[t+dx], a1[t]);
                    }
                }
                int nw = 63 - x0c; if (nw > 8) nw = 8;
                for (int t = 0; t < nw; t++) tc[y0*68 + 3 + x0c + t] = a1[t];
            }
            __syncthreads();
            if (act){
                for (int dy = 0; dy < 7; dy++){
                    int ry = y0 + dy - 3;
                    if (ry < 0 || ry >= 63) continue;
                    W16 w16;
                    const float4* tp = (const float4*)(tc + ry*68 + x0c);
                    w16.v[0]=tp[0]; w16.v[1]=tp[1]; w16.v[2]=tp[2]; w16.v[3]=tp[3];
                    #pragma unroll
                    for (int dx = 0; dx < 7; dx++){
                        float wv = w2s[c*49 + dy*7 + dx];
                        #pragma unroll
                        for (int t = 0; t < 8; t++) acc2[t] = fmaf(wv, w16.a[t+dx], acc2[t]);
                    }
                }
            }
            __syncthreads();
        }
        if (act){
            int nw = 63 - x0c; if (nw > 8) nw = 8;
            for (int t = 0; t < nw; t++) xs[y0*68 + x0c + t] += acc2[t];
        }
        __syncthreads();
        for (int i = tid; i < 4096; i += 512){
            int y = i >> 6, xx = i & 63;
            float val = 0.f;
            if (y < 63 && xx < 63){
                float s = 0.f;
                #pragma unroll
                for (int dy = 0; dy < 3; dy++){
                    int u = y + dy;
                    #pragma unroll
                    for (int dx = 0; dx < 3; dx++){
                        int v = xx + dx;
                        float p;
                        if (u == 64 || v == 64)    p = 1.0f;
                        else if (u == 0 || v == 0) p = 0.0f;
                        else                       p = xs[(u-1)*68 + (v-1)];
                        s = fmaf(p, ka[dy*3 + dx], s);
                    }
                }
                val = fg[y*ND + xx] - s;
            }
            rP[i] = val;
        }
        __syncthreads();
        {
            float tr0=0.f,ti0=0.f,tr1=0.f,ti1=0.f,tr2=0.f,ti2=0.f,tr3=0.f,ti3=0.f;
            for (int m = 0; m < 63; m++){
                float fr = Fs_r[m*64 + kt], fi = Fs_i[m*64 + kt];
                F4 rv; rv.v = rP4[m*16 + cg];
                tr0 = fmaf(fr, rv.a[0], tr0); ti0 = fmaf(fi, rv.a[0], ti0);
                tr1 = fmaf(fr, rv.a[1], tr1); ti1 = fmaf(fi, rv.a[1], ti1);
                tr2 = fmaf(fr, rv.a[2], tr2); ti2 = fmaf(fi, rv.a[2], ti2);
                tr3 = fmaf(fr, rv.a[3], tr3); ti3 = fmaf(fi, rv.a[3], ti3);
            }
            const int c0 = 4*cg;
            TtC[(c0+0)*32 + ((kt + c0 + 0) & 31)] = make_float2(tr0, ti0);
            TtC[(c0+1)*32 + ((kt + c0 + 1) & 31)] = make_float2(tr1, ti1);
            TtC[(c0+2)*32 + ((kt + c0 + 2) & 31)] = make_float2(tr2, ti2);
            TtC[(c0+3)*32 + ((kt + c0 + 3) & 31)] = make_float2(tr3, ti3);
        }
        __syncthreads();
        {
            float R0r=0.f,R0i=0.f,R1r=0.f,R1i=0.f,R2r=0.f,R2i=0.f,R3r=0.f,R3i=0.f;
            for (int n = 0; n < 63; n++){
                float2 T = TtC[n*32 + ((kt + n) & 31)];
                F4 fr, fi;
                fr.v = F4r[n*16 + cg];
                fi.v = F4i[n*16 + cg];
                R0r = fmaf(T.x, fr.a[0], R0r); R0r = fmaf(-T.y, fi.a[0], R0r);
                R0i = fmaf(T.x, fi.a[0], R0i); R0i = fmaf( T.y, fr.a[0], R0i);
                R1r = fmaf(T.x, fr.a[1], R1r); R1r = fmaf(-T.y, fi.a[1], R1r);
                R1i = fmaf(T.x, fi.a[1], R1i); R1i = fmaf( T.y, fr.a[1], R1i);
                R2r = fmaf(T.x, fr.a[2], R2r); R2r = fmaf(-T.y, fi.a[2], R2r);
                R2i = fmaf(T.x, fi.a[2], R2i); R2i = fmaf( T.y, fr.a[2], R2i);
                R3r = fmaf(T.x, fr.a[3], R3r); R3r = fmaf(-T.y, fi.a[3], R3r);
                R3i = fmaf(T.x, fi.a[3], R3i); R3i = fmaf( T.y, fr.a[3], R3i);
            }
            if (cg == 0){
                float2 dv = ((const float2*)dvs)[kt];
                ds_r[kt] = R0r*dv.x + R0i*dv.y;
                ds_i[kt] = R0r*dv.y - R0i*dv.x;
            }
            float4 vA = vc4s[kt*32 + 2*cg];
            float4 vB = vc4s[kt*32 + 2*cg + 1];
            const int c0 = 4*cg, rot = kt;
            MC2[kt*64 + ((c0+0 + rot) & 63)] = make_float2(R0r*vA.x - R0i*vA.y, R0r*vA.y + R0i*vA.x);
            MC2[kt*64 + ((c0+1 + rot) & 63)] = make_float2(R1r*vA.z - R1i*vA.w, R1r*vA.w + R1i*vA.z);
            MC2[kt*64 + ((c0+2 + rot) & 63)] = make_float2(R2r*vB.x - R2i*vB.y, R2r*vB.y + R2i*vB.x);
            MC2[kt*64 + ((c0+3 + rot) & 63)] = make_float2(R3r*vB.z - R3i*vB.w, R3r*vB.w + R3i*vB.z);
        }
        __syncthreads();
        {
            float C0r=0.f,C0i=0.f,C1r=0.f,C1i=0.f,C2r=0.f,C2i=0.f,C3r=0.f,C3i=0.f;
            const int rot = kt;
            for (int l = 0; l < 63; l++){
                float2 Mv = MC2[kt*64 + ((l + rot) & 63)];
                F4 fr, fi;
                fr.v = F4r[l*16 + cg];
                fi.v = F4i[l*16 + cg];
                C0r = fmaf(Mv.x, fr.a[0], C0r); C0r = fmaf( Mv.y, fi.a[0], C0r);
                C0i = fmaf(Mv.y, fr.a[0], C0i); C0i = fmaf(-Mv.x, fi.a[0], C0i);
                C1r = fmaf(Mv.x, fr.a[1], C1r); C1r = fmaf( Mv.y, fi.a[1], C1r);
                C1i = fmaf(Mv.y, fr.a[1], C1i); C1i = fmaf(-Mv.x, fi.a[1], C1i);
                C2r = fmaf(Mv.x, fr.a[2], C2r); C2r = fmaf( Mv.y, fi.a[2], C2r);
                C2i = fmaf(Mv.y, fr.a[2], C2i); C2i = fmaf(-Mv.x, fi.a[2], C2i);
                C3r = fmaf(Mv.x, fr.a[3], C3r); C3r = fmaf( Mv.y, fi.a[3], C3r);
                C3i = fmaf(Mv.y, fr.a[3], C3i); C3i = fmaf(-Mv.x, fi.a[3], C3i);
            }
            float sc2 = (kt == 0) ? 0.5f : 1.0f;
            CC4[kt*33 + 2*cg]     = make_float4(C0r*sc2, C0i*sc2, C1r*sc2, C1i*sc2);
            CC4[kt*33 + 2*cg + 1] = make_float4(C2r*sc2, C2i*sc2, C3r*sc2, C3i*sc2);
        }
        __syncthreads();
        {
            const int p = tid >> 3, qb = tid & 7;
            if (p < 63){
                float y0v=0.f,y1v=0.f,y2v=0.f,y3v=0.f,y4v=0.f,y5v=0.f,y6v=0.f,y7v=0.f,e=0.f;
                for (int n = 0; n < 32; n++){
                    float fr = Fs_r[n*64 + p], fi = Fs_i[n*64 + p];
                    float4 cA = CC4[n*33 + qb];
                    float4 cB = CC4[n*33 + qb + 8];
                    float4 cC = CC4[n*33 + qb + 16];
                    float4 cD = CC4[n*33 + qb + 24];
                    y0v = fmaf(fr, cA.x, y0v); y0v = fmaf(fi, cA.y, y0v);
                    y1v = fmaf(fr, cA.z, y1v); y1v = fmaf(fi, cA.w, y1v);
                    y2v = fmaf(fr, cB.x, y2v); y2v = fmaf(fi, cB.y, y2v);
                    y3v = fmaf(fr, cB.z, y3v); y3v = fmaf(fi, cB.w, y3v);
                    y4v = fmaf(fr, cC.x, y4v); y4v = fmaf(fi, cC.y, y4v);
                    y5v = fmaf(fr, cC.z, y5v); y5v = fmaf(fi, cC.w, y5v);
                    y6v = fmaf(fr, cD.x, y6v); y6v = fmaf(fi, cD.y, y6v);
                    y7v = fmaf(fr, cD.z, y7v); y7v = fmaf(fi, cD.w, y7v);
                    e  = fmaf(fr, ds_r[n], e); e = fmaf(-fi, ds_i[n], e);
                }
                float* xrow = xs + p*68;
                float2* xp0 = (float2*)(xrow + 2*qb);
                float2* xp1 = (float2*)(xrow + 2*qb + 16);
                float2* xp2 = (float2*)(xrow + 2*qb + 32);
                float2* xp3 = (float2*)(xrow + 2*qb + 48);
                float2 v0 = *xp0, v1 = *xp1, v2 = *xp2, v3 = *xp3;
                v0.x += 2.f*y0v + e; v0.y += 2.f*y1v + e;
                v1.x += 2.f*y2v + e; v1.y += 2.f*y3v + e;
                v2.x += 2.f*y4v + e; v2.y += 2.f*y5v + e;
                v3.x += 2.f*y6v + e; v3.y += 2.f*y7v + e;
                *xp0 = v0; *xp1 = v1; *xp2 = v2; *xp3 = v3;
            }
        }
        __syncthreads();
    }
    float s = 0.f;
    for (int i = tid; i < NN; i += 512){
        int y = i / ND, xx = i % ND;
        float cv = 0.f;
        #pragma unroll
        for (int dy = 0; dy < 3; dy++){
            int u = y + dy;
            #pragma unroll
            for (int dx = 0; dx < 3; dx++){
                int v = xx + dx;
                float p;
                if (u == 64 || v == 64)    p = 1.0f;
                else if (u == 0 || v == 0) p = 0.0f;
                else                       p = xs[(u-1)*68 + (v-1)];
                cv = fmaf(p, ka[dy*3 + dx], cv);
            }
        }
        float r = fg[i] - cv;
        s = fmaf(r, r, s);
    }
    #pragma unroll
    for (int off = 32; off > 0; off >>= 1) s += __shfl_down(s, off, 64);
    int lane = tid & 63, w = tid >> 6;
    if (lane == 0) red[w] = s;
    __syncthreads();
    if (tid == 0){
        float t = 0.f;
        #pragma unroll
        for (int i = 0; i < 8; i++) t += red[i];
        atomicAdd(accg, t);
    }
}

__global__ void k_final(const float* __restrict__ acc, float* __restrict__ out){
    if (threadIdx.x == 0 && blockIdx.x == 0) out[0] = sqrtf(acc[0]) * (1.0f/256.0f);
}

// ---------------- host ------------------------------------------------------
extern "C" void kernel_launch(void* const* d_in, const int* in_sizes, int n_in,
                              void* d_out, int out_size, void* d_ws, size_t ws_size,
                              hipStream_t stream){
    const float* x0     = (const float*)d_in[0];
    const float* f      = (const float*)d_in[1];
    const float* kA     = (const float*)d_in[2];
    const float* fc1_w1 = (const float*)d_in[3];
    const float* fc1_b1 = (const float*)d_in[4];
    const float* fc1_w2 = (const float*)d_in[5];
    const float* fc1_b2 = (const float*)d_in[6];
    const float* fc2_w1 = (const float*)d_in[7];
    const float* fc2_b1 = (const float*)d_in[8];
    const float* fc2_w2 = (const float*)d_in[9];
    const float* fc2_b2 = (const float*)d_in[10];
    const float* ct1_w  = (const float*)d_in[11];
    const float* ct1_b  = (const float*)d_in[12];
    const float* ct2_w  = (const float*)d_in[13];
    const float* ct2_b  = (const float*)d_in[14];
    const float* ct3_w  = (const float*)d_in[15];
    const float* ct3_b  = (const float*)d_in[16];
    const float* ct4_w  = (const float*)d_in[17];
    const float* ct4_b  = (const float*)d_in[18];
    const float* ct5_w  = (const float*)d_in[19];
    const float* ct5_b  = (const float*)d_in[20];
    float* out = (float*)d_out;

    float* ws = (float*)d_ws;
    size_t off = 0;
    auto take = [&](size_t n){ float* p = ws + off; off += (n + 63) & ~(size_t)63; return p; };
    float* acc = take(64);
    float* c3  = take((size_t)NB*32*289);
    float* c4  = take((size_t)NB*32*1089);
    (void)ws_size; (void)in_sizes; (void)n_in; (void)out_size;

    k_ct123<<<NB, 512, 0, stream>>>(kA, ct1_w, ct2_w, ct3_w,
                                    ct1_b, ct2_b, ct3_b, c3, acc);
    k_ct4<<<NB*2, 512, 0, stream>>>(c3, ct4_w, ct4_b, c4);
    k_solve<<<NB, 512, 0, stream>>>(x0, f, kA,
                                    fc1_w1, fc1_b1, fc1_w2, fc1_b2,
                                    fc2_w1, fc2_b1, fc2_w2, fc2_b2,
                                    ct5_w, ct5_b, c4, acc);
    k_final<<<1, 64, 0, stream>>>(acc, out);
}